// Round 2
// baseline (555.871 us; speedup 1.0000x reference)
//
#include <hip/hip_runtime.h>
#include <math.h>

#define BB 2
#define LL 384
#define DD 256
#define HH 8
#define DHH 32

// workspace layout (float offsets)
// q   [B,L,D]          196608
// kk  [B,H,L,DH]       196608
// vv  [B,H,L,DH]       196608
// w   [B,L,H,D]        1572864
// cbr [B,L,H]          6144
static const size_t OFF_Q   = 0;
static const size_t OFF_KK  = 196608;
static const size_t OFF_VV  = 393216;
static const size_t OFF_W   = 589824;
static const size_t OFF_CBR = 2162688;

__device__ __forceinline__ float dot4(float4 a, float4 b) {
    return a.x * b.x + a.y * b.y + a.z * b.z + a.w * b.w;
}

// ---------------------------------------------------------------------------
// A1: projections  y = x @ W^T + b  for q (layout [B,L,D]) and k,v ([B,H,L,DH])
// grid 288 = 3 mats * B * (L/8); 256 threads; 8-row ltile staged in LDS,
// thread t owns output column n=t, W row read via L1-cached strided loads.
// ---------------------------------------------------------------------------
__global__ __launch_bounds__(256) void k_proj(
    const float* __restrict__ Xq, const float* __restrict__ Xk, const float* __restrict__ Xv,
    const float* __restrict__ Wq, const float* __restrict__ Wk, const float* __restrict__ Wv,
    const float* __restrict__ bq, const float* __restrict__ bk, const float* __restrict__ bv,
    float* __restrict__ oq, float* __restrict__ okk, float* __restrict__ ovv)
{
    int bx = blockIdx.x;
    int mat = bx / 96;
    int rem = bx % 96;
    int b = rem / 48;
    int l0 = (rem % 48) * 8;
    const float* X = (mat == 0) ? Xq : (mat == 1) ? Xk : Xv;
    const float* W = (mat == 0) ? Wq : (mat == 1) ? Wk : Wv;
    const float* bias = (mat == 0) ? bq : (mat == 1) ? bk : bv;

    __shared__ float xs[8 * 256];
    int tid = threadIdx.x;
    {
        const float4* src = (const float4*)(X + (size_t)(b * LL + l0) * DD);
        float4* dst = (float4*)xs;
        dst[tid] = src[tid];
        dst[tid + 256] = src[tid + 256];
    }
    __syncthreads();

    int n = tid;
    float bn = bias[n];
    float acc[8];
#pragma unroll
    for (int l = 0; l < 8; ++l) acc[l] = bn;

    const float4* wrow = (const float4*)(W + (size_t)n * DD);
#pragma unroll 8
    for (int kc = 0; kc < 64; ++kc) {
        float4 wv = wrow[kc];
#pragma unroll
        for (int l = 0; l < 8; ++l) {
            float4 xv = ((const float4*)(xs + l * 256))[kc];
            acc[l] += dot4(wv, xv);
        }
    }

    if (mat == 0) {
#pragma unroll
        for (int l = 0; l < 8; ++l)
            oq[(size_t)(b * LL + l0 + l) * DD + n] = acc[l];
    } else {
        float* o = (mat == 1) ? okk : ovv;
        int h = n >> 5, dh = n & 31;
#pragma unroll
        for (int l = 0; l < 8; ++l)
            o[((size_t)(b * HH + h) * LL + l0 + l) * DHH + dh] = acc[l];
    }
}

// ---------------------------------------------------------------------------
// A2: w[b,l,h,d] = sum_dh (q+v)[b,h,l,dh] * Wr[h*32+dh, d];  cbr = (q+v)·br
// grid 192 = B*L/4; 256 threads (4 l-rows x 64 lanes, lane owns 4 d's)
// ---------------------------------------------------------------------------
__global__ __launch_bounds__(256) void k_wproj(
    const float* __restrict__ q, const float* __restrict__ vpar,
    const float* __restrict__ Wr, const float* __restrict__ br,
    float* __restrict__ w, float* __restrict__ cbr)
{
    int b = blockIdx.x / 96;
    int l0 = (blockIdx.x % 96) * 4;
    int tid = threadIdx.x;
    int gq = tid >> 6;
    int lane = tid & 63;

    __shared__ float qv[4][256];
    {
        const float4* qsrc = (const float4*)(q + (size_t)(b * LL + l0 + gq) * DD);
        const float4* vsrc = (const float4*)vpar;
        float4 t = qsrc[lane];
        float4 vv4 = vsrc[lane];
        t.x += vv4.x; t.y += vv4.y; t.z += vv4.z; t.w += vv4.w;
        ((float4*)qv[gq])[lane] = t;
    }
    __syncthreads();

    int l = l0 + gq;
    int d4 = lane * 4;
    float* wbase = w + ((size_t)(b * LL + l) * HH) * DD + d4;
    for (int h = 0; h < HH; ++h) {
        float4 acc = make_float4(0.f, 0.f, 0.f, 0.f);
#pragma unroll 8
        for (int dh = 0; dh < 32; ++dh) {
            float s = qv[gq][h * 32 + dh];
            float4 wr4 = *(const float4*)(Wr + (size_t)(h * 32 + dh) * DD + d4);
            acc.x += s * wr4.x; acc.y += s * wr4.y; acc.z += s * wr4.z; acc.w += s * wr4.w;
        }
        *(float4*)(wbase + h * DD) = acc;
    }

    if (tid < 32) {
        int g2 = tid >> 3, hh = tid & 7;
        float s = 0.f;
#pragma unroll 8
        for (int dh = 0; dh < 32; ++dh)
            s += qv[g2][hh * 32 + dh] * br[hh * 32 + dh];
        cbr[(size_t)(b * LL + l0 + g2) * HH + hh] = s;
    }
}

// ---------------------------------------------------------------------------
// Fused BD + AC + softmax + PV.  One block per (b,q); score lives in LDS only.
//   phase 0: stage qu = q+u (LDS); issue w-fragment loads (128 VGPR/lane)
//   phase 2: sc[h][k] = ((q+u)·k + cbr)*inv - pen      (k rows L2-hot)
//   phase 1: sc[h][k] += inv * pos[b,q,k,:]·w[b,q,h,:]  (the 302 MB stream)
//   phase 3: per-wave softmax of 2 h-rows
//   phase 4: out[h,dh] = sum_k sc[h][k]*val[b,h,k,dh]   (coalesced 128B reads)
// __launch_bounds__(256,3): cap ~170 VGPR so all 768 blocks co-resident (3/CU).
// ---------------------------------------------------------------------------
__global__ __launch_bounds__(256, 3) void k_fused(
    const float* __restrict__ pos, const float* __restrict__ w,
    const float* __restrict__ q, const float* __restrict__ u,
    const float* __restrict__ kk, const float* __restrict__ vv,
    const float* __restrict__ cbr, const float* __restrict__ mask,
    float* __restrict__ out)
{
    int b = blockIdx.x / LL;
    int qi = blockIdx.x % LL;
    int tid = threadIdx.x;
    int wave = tid >> 6;
    int lane = tid & 63;
    int g = lane & 15;
    int r = lane >> 4;

    __shared__ float sc[HH][LL];  // 12 KB score tile
    __shared__ float qu[DD];

    const float inv = 0.17677669529663687f; // 1/sqrt(32)

    // --- w fragment: 8h x 16d per lane (lane g owns d = 4g + 64j) ---
    const float* wb = w + ((size_t)(b * LL + qi) * HH) * DD + g * 4;
    float4 wr[8][4];
#pragma unroll
    for (int h = 0; h < 8; ++h) {
#pragma unroll
        for (int j = 0; j < 4; ++j)
            wr[h][j] = *(const float4*)(wb + h * DD + j * 64);
    }

    // --- stage q+u ---
    qu[tid] = q[(size_t)(b * LL + qi) * DD + tid] + u[tid];
    __syncthreads();

    // --- phase 2: AC init of score tile. thread t -> h=t>>5, k in [(t&31)*12, +12) ---
    {
        int h = tid >> 5;
        int kb = (tid & 31) * 12;
        float cb = cbr[(size_t)(b * LL + qi) * HH + h];
        const float4* qp = (const float4*)(qu + h * 32);
#pragma unroll 2
        for (int j = 0; j < 12; ++j) {
            int k = kb + j;
            const float4* krow = (const float4*)(kk + ((size_t)(b * HH + h) * LL + k) * DHH);
            float acc = 0.f;
#pragma unroll
            for (int jj = 0; jj < 8; ++jj) acc += dot4(qp[jj], krow[jj]);
            float pen = (1.0f - mask[b * LL + k]) * 1e15f;
            sc[h][k] = (acc + cb) * inv - pen;
        }
    }
    __syncthreads();

    // --- phase 1: the pos stream (wave owns k-rows wave*4+r, step 16) ---
    const float* posq = pos + (size_t)(b * LL + qi) * LL * DD + g * 4;
#pragma unroll 1
    for (int k0 = wave * 4; k0 < LL; k0 += 16) {
        int krow = k0 + r;
        const float* pr = posq + (size_t)krow * DD;
        float4 p0 = *(const float4*)(pr);
        float4 p1 = *(const float4*)(pr + 64);
        float4 p2 = *(const float4*)(pr + 128);
        float4 p3 = *(const float4*)(pr + 192);
        float acc[8];
#pragma unroll
        for (int h = 0; h < 8; ++h)
            acc[h] = dot4(p0, wr[h][0]) + dot4(p1, wr[h][1]) +
                     dot4(p2, wr[h][2]) + dot4(p3, wr[h][3]);
#pragma unroll
        for (int m = 1; m <= 8; m <<= 1) {
#pragma unroll
            for (int h = 0; h < 8; ++h)
                acc[h] += __shfl_xor(acc[h], m, 64);
        }
        if (g == 0) {
#pragma unroll
            for (int h = 0; h < 8; ++h)
                sc[h][krow] += acc[h] * inv;
        }
    }
    __syncthreads();

    // --- phase 3: softmax, wave handles h = 2*wave + ri ---
#pragma unroll
    for (int ri = 0; ri < 2; ++ri) {
        int h = wave * 2 + ri;
        float s[6];
#pragma unroll
        for (int j = 0; j < 6; ++j) s[j] = sc[h][lane + 64 * j];
        float m = s[0];
#pragma unroll
        for (int j = 1; j < 6; ++j) m = fmaxf(m, s[j]);
#pragma unroll
        for (int off = 1; off < 64; off <<= 1) m = fmaxf(m, __shfl_xor(m, off, 64));
        float e[6];
        float ls = 0.f;
#pragma unroll
        for (int j = 0; j < 6; ++j) { e[j] = __expf(s[j] - m); ls += e[j]; }
#pragma unroll
        for (int off = 1; off < 64; off <<= 1) ls += __shfl_xor(ls, off, 64);
        float rinv = 1.0f / ls;
#pragma unroll
        for (int j = 0; j < 6; ++j) sc[h][lane + 64 * j] = e[j] * rinv;
    }
    __syncthreads();

    // --- phase 4: PV. thread t -> (h=t>>5, dh=t&31); 128B-coalesced val reads ---
    {
        int h = tid >> 5, dh = tid & 31;
        const float* vb = vv + ((size_t)(b * HH + h) * LL) * DHH + dh;
        float acc = 0.f;
#pragma unroll 1
        for (int k = 0; k < LL; k += 4) {
            float v0 = vb[(size_t)(k + 0) * DHH];
            float v1 = vb[(size_t)(k + 1) * DHH];
            float v2 = vb[(size_t)(k + 2) * DHH];
            float v3 = vb[(size_t)(k + 3) * DHH];
            acc += sc[h][k + 0] * v0 + sc[h][k + 1] * v1 +
                   sc[h][k + 2] * v2 + sc[h][k + 3] * v3;
        }
        out[(size_t)(b * LL + qi) * DD + h * 32 + dh] = acc;
    }
}

extern "C" void kernel_launch(void* const* d_in, const int* in_sizes, int n_in,
                              void* d_out, int out_size, void* d_ws, size_t ws_size,
                              hipStream_t stream) {
    const float* key    = (const float*)d_in[0];
    const float* query  = (const float*)d_in[1];
    const float* value  = (const float*)d_in[2];
    const float* pos    = (const float*)d_in[3];
    const float* kmask  = (const float*)d_in[4];
    const float* Wk     = (const float*)d_in[5];
    const float* bk     = (const float*)d_in[6];
    const float* Wq     = (const float*)d_in[7];
    const float* bq     = (const float*)d_in[8];
    const float* Wv     = (const float*)d_in[9];
    const float* bv     = (const float*)d_in[10];
    const float* Wr     = (const float*)d_in[11];
    const float* br     = (const float*)d_in[12];
    const float* u      = (const float*)d_in[13];
    const float* v      = (const float*)d_in[14];
    float* out = (float*)d_out;

    float* ws = (float*)d_ws;
    float* qbuf   = ws + OFF_Q;
    float* kkbuf  = ws + OFF_KK;
    float* vvbuf  = ws + OFF_VV;
    float* wbuf   = ws + OFF_W;
    float* cbrbuf = ws + OFF_CBR;

    k_proj<<<dim3(288), dim3(256), 0, stream>>>(query, key, value, Wq, Wk, Wv,
                                                bq, bk, bv, qbuf, kkbuf, vvbuf);
    k_wproj<<<dim3(192), dim3(256), 0, stream>>>(qbuf, v, Wr, br, wbuf, cbrbuf);
    k_fused<<<dim3(768), dim3(256), 0, stream>>>(pos, wbuf, qbuf, u, kkbuf, vvbuf,
                                                 cbrbuf, kmask, out);
}

// Round 3
// 537.872 us; speedup vs baseline: 1.0335x; 1.0335x over previous
//
#include <hip/hip_runtime.h>
#include <math.h>

#define BB 2
#define LL 384
#define DD 256
#define HH 8
#define DHH 32

// workspace layout (float offsets)
// q   [B,L,D]          196608
// kk  [B,H,L,DH]       196608
// vv  [B,H,L,DH]       196608
// w   [B,L,H,D]        1572864
// cbr [B,L,H]          6144
static const size_t OFF_Q   = 0;
static const size_t OFF_KK  = 196608;
static const size_t OFF_VV  = 393216;
static const size_t OFF_W   = 589824;
static const size_t OFF_CBR = 2162688;

__device__ __forceinline__ float dot4(float4 a, float4 b) {
    return a.x * b.x + a.y * b.y + a.z * b.z + a.w * b.w;
}

// ---------------------------------------------------------------------------
// A1: projections  y = x @ W^T + b  for q (layout [B,L,D]) and k,v ([B,H,L,DH])
// ---------------------------------------------------------------------------
__global__ __launch_bounds__(256) void k_proj(
    const float* __restrict__ Xq, const float* __restrict__ Xk, const float* __restrict__ Xv,
    const float* __restrict__ Wq, const float* __restrict__ Wk, const float* __restrict__ Wv,
    const float* __restrict__ bq, const float* __restrict__ bk, const float* __restrict__ bv,
    float* __restrict__ oq, float* __restrict__ okk, float* __restrict__ ovv)
{
    int bx = blockIdx.x;
    int mat = bx / 96;
    int rem = bx % 96;
    int b = rem / 48;
    int l0 = (rem % 48) * 8;
    const float* X = (mat == 0) ? Xq : (mat == 1) ? Xk : Xv;
    const float* W = (mat == 0) ? Wq : (mat == 1) ? Wk : Wv;
    const float* bias = (mat == 0) ? bq : (mat == 1) ? bk : bv;

    __shared__ float xs[8 * 256];
    int tid = threadIdx.x;
    {
        const float4* src = (const float4*)(X + (size_t)(b * LL + l0) * DD);
        float4* dst = (float4*)xs;
        dst[tid] = src[tid];
        dst[tid + 256] = src[tid + 256];
    }
    __syncthreads();

    int n = tid;
    float bn = bias[n];
    float acc[8];
#pragma unroll
    for (int l = 0; l < 8; ++l) acc[l] = bn;

    const float4* wrow = (const float4*)(W + (size_t)n * DD);
#pragma unroll 8
    for (int kc = 0; kc < 64; ++kc) {
        float4 wv = wrow[kc];
#pragma unroll
        for (int l = 0; l < 8; ++l) {
            float4 xv = ((const float4*)(xs + l * 256))[kc];
            acc[l] += dot4(wv, xv);
        }
    }

    if (mat == 0) {
#pragma unroll
        for (int l = 0; l < 8; ++l)
            oq[(size_t)(b * LL + l0 + l) * DD + n] = acc[l];
    } else {
        float* o = (mat == 1) ? okk : ovv;
        int h = n >> 5, dh = n & 31;
#pragma unroll
        for (int l = 0; l < 8; ++l)
            o[((size_t)(b * HH + h) * LL + l0 + l) * DHH + dh] = acc[l];
    }
}

// ---------------------------------------------------------------------------
// A2: w[b,l,h,d] = sum_dh (q+v)[b,h,l,dh] * Wr[h*32+dh, d];  cbr = (q+v)·br
// ---------------------------------------------------------------------------
__global__ __launch_bounds__(256) void k_wproj(
    const float* __restrict__ q, const float* __restrict__ vpar,
    const float* __restrict__ Wr, const float* __restrict__ br,
    float* __restrict__ w, float* __restrict__ cbr)
{
    int b = blockIdx.x / 96;
    int l0 = (blockIdx.x % 96) * 4;
    int tid = threadIdx.x;
    int gq = tid >> 6;
    int lane = tid & 63;

    __shared__ float qv[4][256];
    {
        const float4* qsrc = (const float4*)(q + (size_t)(b * LL + l0 + gq) * DD);
        const float4* vsrc = (const float4*)vpar;
        float4 t = qsrc[lane];
        float4 vv4 = vsrc[lane];
        t.x += vv4.x; t.y += vv4.y; t.z += vv4.z; t.w += vv4.w;
        ((float4*)qv[gq])[lane] = t;
    }
    __syncthreads();

    int l = l0 + gq;
    int d4 = lane * 4;
    float* wbase = w + ((size_t)(b * LL + l) * HH) * DD + d4;
    for (int h = 0; h < HH; ++h) {
        float4 acc = make_float4(0.f, 0.f, 0.f, 0.f);
#pragma unroll 8
        for (int dh = 0; dh < 32; ++dh) {
            float s = qv[gq][h * 32 + dh];
            float4 wr4 = *(const float4*)(Wr + (size_t)(h * 32 + dh) * DD + d4);
            acc.x += s * wr4.x; acc.y += s * wr4.y; acc.z += s * wr4.z; acc.w += s * wr4.w;
        }
        *(float4*)(wbase + h * DD) = acc;
    }

    if (tid < 32) {
        int g2 = tid >> 3, hh = tid & 7;
        float s = 0.f;
#pragma unroll 8
        for (int dh = 0; dh < 32; ++dh)
            s += qv[g2][hh * 32 + dh] * br[hh * 32 + dh];
        cbr[(size_t)(b * LL + l0 + g2) * HH + hh] = s;
    }
}

// ---------------------------------------------------------------------------
// Fused BD + AC + softmax + PV.  One block per (b,q); score lives in LDS only.
// Head-split pos stream: wave w -> head-group hg=w>>1 (4 heads), k-phase w&1.
// Fragment is 4h x 16d = 64 VGPRs/lane (fits registers; round-2's 128-VGPR
// fragment was sunk into the loop by the compiler -> latency chain).
// pos is read twice per block (2 head-groups); 2nd pass is L2-hot.
// ---------------------------------------------------------------------------
__global__ __launch_bounds__(256, 3) void k_fused(
    const float* __restrict__ pos, const float* __restrict__ w,
    const float* __restrict__ q, const float* __restrict__ u,
    const float* __restrict__ kk, const float* __restrict__ vv,
    const float* __restrict__ cbr, const float* __restrict__ mask,
    float* __restrict__ out)
{
    int b = blockIdx.x / LL;
    int qi = blockIdx.x % LL;
    int tid = threadIdx.x;
    int wave = tid >> 6;
    int lane = tid & 63;
    int g = lane & 15;
    int r = lane >> 4;
    int hg = wave >> 1;   // head group: heads hg*4 .. hg*4+3
    int kp = wave & 1;    // k phase

    __shared__ float sc[HH][LL];  // 12 KB score tile
    __shared__ float qu[DD];

    const float inv = 0.17677669529663687f; // 1/sqrt(32)

    // --- w fragment: 4h x 16d per lane (lane g owns d = 4g + 64j) ---
    const float* wb = w + ((size_t)(b * LL + qi) * HH + hg * 4) * DD + g * 4;
    float4 wr[4][4];
#pragma unroll
    for (int h = 0; h < 4; ++h) {
#pragma unroll
        for (int j = 0; j < 4; ++j)
            wr[h][j] = *(const float4*)(wb + h * DD + j * 64);
    }

    // --- stage q+u ---
    qu[tid] = q[(size_t)(b * LL + qi) * DD + tid] + u[tid];
    __syncthreads();

    // --- phase 2: AC init. thread t -> h=t>>5, k in [(t&31)*12, +12) ---
    {
        int h = tid >> 5;
        int kb = (tid & 31) * 12;
        float cb = cbr[(size_t)(b * LL + qi) * HH + h];
        const float4* qp = (const float4*)(qu + h * 32);
#pragma unroll 2
        for (int j = 0; j < 12; ++j) {
            int k = kb + j;
            const float4* krow = (const float4*)(kk + ((size_t)(b * HH + h) * LL + k) * DHH);
            float acc = 0.f;
#pragma unroll
            for (int jj = 0; jj < 8; ++jj) acc += dot4(qp[jj], krow[jj]);
            float pen = (1.0f - mask[b * LL + k]) * 1e15f;
            sc[h][k] = (acc + cb) * inv - pen;
        }
    }
    __syncthreads();

    // --- phase 1: pos stream, unroll 2 (8 loads in flight/wave) ---
    // wave covers k rows: kp*4 + r + 8*i  (i = 0..47), two i's per iter
    const float* posq = pos + (size_t)(b * LL + qi) * LL * DD + g * 4;
#pragma unroll 1
    for (int k0 = kp * 4; k0 < LL; k0 += 16) {
        int ka = k0 + r;
        int kb2 = k0 + 8 + r;
        const float* pa = posq + (size_t)ka * DD;
        const float* pb = posq + (size_t)kb2 * DD;
        float4 a0 = *(const float4*)(pa);
        float4 a1 = *(const float4*)(pa + 64);
        float4 a2 = *(const float4*)(pa + 128);
        float4 a3 = *(const float4*)(pa + 192);
        float4 b0 = *(const float4*)(pb);
        float4 b1 = *(const float4*)(pb + 64);
        float4 b2 = *(const float4*)(pb + 128);
        float4 b3 = *(const float4*)(pb + 192);
        float accA[4], accB[4];
#pragma unroll
        for (int h = 0; h < 4; ++h) {
            accA[h] = dot4(a0, wr[h][0]) + dot4(a1, wr[h][1]) +
                      dot4(a2, wr[h][2]) + dot4(a3, wr[h][3]);
            accB[h] = dot4(b0, wr[h][0]) + dot4(b1, wr[h][1]) +
                      dot4(b2, wr[h][2]) + dot4(b3, wr[h][3]);
        }
#pragma unroll
        for (int m = 1; m <= 8; m <<= 1) {
#pragma unroll
            for (int h = 0; h < 4; ++h) {
                accA[h] += __shfl_xor(accA[h], m, 64);
                accB[h] += __shfl_xor(accB[h], m, 64);
            }
        }
        if (g == 0) {
#pragma unroll
            for (int h = 0; h < 4; ++h) {
                sc[hg * 4 + h][ka]  += accA[h] * inv;
                sc[hg * 4 + h][kb2] += accB[h] * inv;
            }
        }
    }
    __syncthreads();

    // --- phase 3: softmax, wave handles h = 2*wave + ri ---
#pragma unroll
    for (int ri = 0; ri < 2; ++ri) {
        int h = wave * 2 + ri;
        float s[6];
#pragma unroll
        for (int j = 0; j < 6; ++j) s[j] = sc[h][lane + 64 * j];
        float m = s[0];
#pragma unroll
        for (int j = 1; j < 6; ++j) m = fmaxf(m, s[j]);
#pragma unroll
        for (int off = 1; off < 64; off <<= 1) m = fmaxf(m, __shfl_xor(m, off, 64));
        float e[6];
        float ls = 0.f;
#pragma unroll
        for (int j = 0; j < 6; ++j) { e[j] = __expf(s[j] - m); ls += e[j]; }
#pragma unroll
        for (int off = 1; off < 64; off <<= 1) ls += __shfl_xor(ls, off, 64);
        float rinv = 1.0f / ls;
#pragma unroll
        for (int j = 0; j < 6; ++j) sc[h][lane + 64 * j] = e[j] * rinv;
    }
    __syncthreads();

    // --- phase 4: PV. thread t -> (h=t>>5, dh=t&31); unroll 8 for ILP ---
    {
        int h = tid >> 5, dh = tid & 31;
        const float* vb = vv + ((size_t)(b * HH + h) * LL) * DHH + dh;
        float acc = 0.f;
#pragma unroll 1
        for (int k = 0; k < LL; k += 8) {
            float vs[8];
#pragma unroll
            for (int j = 0; j < 8; ++j) vs[j] = vb[(size_t)(k + j) * DHH];
#pragma unroll
            for (int j = 0; j < 8; ++j) acc += sc[h][k + j] * vs[j];
        }
        out[(size_t)(b * LL + qi) * DD + h * 32 + dh] = acc;
    }
}

extern "C" void kernel_launch(void* const* d_in, const int* in_sizes, int n_in,
                              void* d_out, int out_size, void* d_ws, size_t ws_size,
                              hipStream_t stream) {
    const float* key    = (const float*)d_in[0];
    const float* query  = (const float*)d_in[1];
    const float* value  = (const float*)d_in[2];
    const float* pos    = (const float*)d_in[3];
    const float* kmask  = (const float*)d_in[4];
    const float* Wk     = (const float*)d_in[5];
    const float* bk     = (const float*)d_in[6];
    const float* Wq     = (const float*)d_in[7];
    const float* bq     = (const float*)d_in[8];
    const float* Wv     = (const float*)d_in[9];
    const float* bv     = (const float*)d_in[10];
    const float* Wr     = (const float*)d_in[11];
    const float* br     = (const float*)d_in[12];
    const float* u      = (const float*)d_in[13];
    const float* v      = (const float*)d_in[14];
    float* out = (float*)d_out;

    float* ws = (float*)d_ws;
    float* qbuf   = ws + OFF_Q;
    float* kkbuf  = ws + OFF_KK;
    float* vvbuf  = ws + OFF_VV;
    float* wbuf   = ws + OFF_W;
    float* cbrbuf = ws + OFF_CBR;

    k_proj<<<dim3(288), dim3(256), 0, stream>>>(query, key, value, Wq, Wk, Wv,
                                                bq, bk, bv, qbuf, kkbuf, vvbuf);
    k_wproj<<<dim3(192), dim3(256), 0, stream>>>(qbuf, v, Wr, br, wbuf, cbrbuf);
    k_fused<<<dim3(768), dim3(256), 0, stream>>>(pos, wbuf, qbuf, u, kkbuf, vvbuf,
                                                 cbrbuf, kmask, out);
}